// Round 5
// baseline (741.913 us; speedup 1.0000x reference)
//
#include <hip/hip_runtime.h>
#include <math.h>

#define HEAD 128
typedef _Float16 f16;
typedef _Float16 f16x8 __attribute__((ext_vector_type(8)));
typedef float f32x4 __attribute__((ext_vector_type(4)));

// ---------------- compile-time Möbius band table ----------------
constexpr int mu_of(int n) {
  int m = n, cnt = 0;
  for (int p = 2; p * p <= m; ++p) {
    if (m % p == 0) {
      m /= p; ++cnt;
      if (m % p == 0) return 0;
    }
  }
  if (m > 1) ++cnt;
  return (cnt & 1) ? -1 : 1;
}
constexpr int key_of(int idx) {
  int mu = mu_of(idx + 1);
  return mu == 1 ? 0 : (mu == 0 ? 1 : 2);
}
struct Tbl {
  int band[HEAD];
  float qm[HEAD];
};
constexpr Tbl make_tbl() {
  Tbl t{};
  constexpr float qv[4] = {15.f, 7.f, 7.f, 3.f};
  for (int p = 0; p < HEAD; ++p) {
    int kp = key_of(p);
    int rank = 0;
    for (int j = 0; j < HEAD; ++j) {
      int kj = key_of(j);
      if (kj < kp || (kj == kp && j < p)) ++rank;
    }
    t.band[p] = rank >> 5;
    t.qm[p] = qv[rank >> 5];
  }
  return t;
}
__constant__ Tbl g_tbl = make_tbl();

// ------- fused f32 -> (hi,lo) f16 split for x and W, pre-scaled by 64 ------
__global__ __launch_bounds__(256) void split_all(
    const float* __restrict__ x, const float* __restrict__ W,
    f16* __restrict__ xh, f16* __restrict__ xl,
    f16* __restrict__ wh, f16* __restrict__ wl,
    long n8x, long n8tot) {
  long i = blockIdx.x * (long)blockDim.x + threadIdx.x;
  long stride = (long)gridDim.x * blockDim.x;
  for (; i < n8tot; i += stride) {
    const float* s;
    f16 *h, *l;
    long j;
    if (i < n8x) {
      s = x; h = xh; l = xl; j = i;
    } else {
      s = W; h = wh; l = wl; j = i - n8x;
    }
    const float4* p = (const float4*)s + 2 * j;
    float4 a = p[0], c = p[1];
    float v[8] = {a.x, a.y, a.z, a.w, c.x, c.y, c.z, c.w};
    f16x8 hv, lv;
#pragma unroll
    for (int t = 0; t < 8; ++t) {
      float sv = v[t] * 64.f;
      f16 ht = (f16)sv;
      hv[t] = ht;
      lv[t] = (f16)(sv - (float)ht);
    }
    ((f16x8*)h)[j] = hv;
    ((f16x8*)l)[j] = lv;
  }
}

// ---------------- async global->LDS, 16B ----------------
__device__ __forceinline__ void dma16(const f16* g, f16* l) {
  __builtin_amdgcn_global_load_lds(
      (const __attribute__((address_space(1))) unsigned int*)g,
      (__attribute__((address_space(3))) unsigned int*)l, 16, 0, 0);
}

// ---------------- MFMA GEMM: C[M,N] = (Ah+Al)(Bh+Bl)^T /4096 + bias --------
// 1 wave per block; 64x64 tile; BK=64; 3-term f16 split (AlBl dropped).
// Chunk-major staging (lane = row%16 + 16*(chunk%4)) -> frag ds_read_b128
// is 2-way bank aliased only (free, m136); verified 0 conflicts in R4.
__global__ __launch_bounds__(64) void gemm_f16split(
    const f16* __restrict__ Ah, const f16* __restrict__ Al,
    const f16* __restrict__ Bh, const f16* __restrict__ Bl,
    const float* __restrict__ bias, float* __restrict__ C,
    int M, int N, int K) {
  __shared__ f16 sAh[4096], sAl[4096], sBh[4096], sBl[4096];  // 8KB each

  const int lane = threadIdx.x;
  const int m0 = blockIdx.x * 64;
  const int n0 = blockIdx.y * 64;

  // staging: lane covers (row = 16s + lane&15, col-chunk = 4h + lane>>4)
  const int srow = lane & 15;
  const int scol = (lane >> 4) * 8;
  const f16* gAh = Ah + (size_t)(m0 + srow) * K + scol;
  const f16* gAl = Al + (size_t)(m0 + srow) * K + scol;
  const f16* gBh = Bh + (size_t)(n0 + srow) * K + scol;
  const f16* gBl = Bl + (size_t)(n0 + srow) * K + scol;
  const size_t rstep = (size_t)16 * K;  // 16 rows

  f32x4 acc[4][4];
#pragma unroll
  for (int i = 0; i < 4; ++i)
#pragma unroll
    for (int j = 0; j < 4; ++j) acc[i][j] = (f32x4){0.f, 0.f, 0.f, 0.f};

  // DMA (s,h) -> LDS f16 offset s*1024 + h*512 + lane*8
#define STAGE(kofs)                                                    \
  do {                                                                 \
    _Pragma("unroll") for (int s = 0; s < 4; ++s) {                    \
      _Pragma("unroll") for (int h = 0; h < 2; ++h) {                  \
        const size_t go = (kofs) + s * rstep + h * 32;                 \
        const int lo = s * 1024 + h * 512;                             \
        dma16(gAh + go, &sAh[lo]);                                     \
        dma16(gAl + go, &sAl[lo]);                                     \
        dma16(gBh + go, &sBh[lo]);                                     \
        dma16(gBl + go, &sBl[lo]);                                     \
      }                                                                \
    }                                                                  \
  } while (0)

  STAGE(0);

  const int frow = lane & 15;
  const int kq = lane >> 4;  // 0..3
  // element (row frow, kstep st, chunk kq) at s*1024 + st*512 + frow*8 + kq*128
  const int fbase = frow * 8 + kq * 128;

  const int nIter = K / 64;
  for (int it = 0; it < nIter; ++it) {
    __syncthreads();  // drains vmcnt(0): tile resident in LDS
    f16x8 ah[2][4], al[2][4], bh[2][4], bl[2][4];
#pragma unroll
    for (int st = 0; st < 2; ++st)
#pragma unroll
      for (int s = 0; s < 4; ++s) {
        const int o = s * 1024 + st * 512 + fbase;
        ah[st][s] = *(const f16x8*)&sAh[o];
        al[st][s] = *(const f16x8*)&sAl[o];
        bh[st][s] = *(const f16x8*)&sBh[o];
        bl[st][s] = *(const f16x8*)&sBl[o];
      }
    __syncthreads();  // drains lgkmcnt(0): frags in regs, LDS reusable
    if (it + 1 < nIter) STAGE((size_t)(it + 1) * 64);

#pragma unroll
    for (int st = 0; st < 2; ++st)
#pragma unroll
      for (int i = 0; i < 4; ++i)
#pragma unroll
        for (int j = 0; j < 4; ++j) {
          acc[i][j] = __builtin_amdgcn_mfma_f32_16x16x32_f16(ah[st][i], bh[st][j], acc[i][j], 0, 0, 0);
          acc[i][j] = __builtin_amdgcn_mfma_f32_16x16x32_f16(al[st][i], bh[st][j], acc[i][j], 0, 0, 0);
          acc[i][j] = __builtin_amdgcn_mfma_f32_16x16x32_f16(ah[st][i], bl[st][j], acc[i][j], 0, 0, 0);
        }
  }

  // epilogue: C/D layout col=lane&15, row=(lane>>4)*4+r
  const float inv = 1.f / 4096.f;
#pragma unroll
  for (int j = 0; j < 4; ++j) {
    const int col = n0 + j * 16 + frow;
    const float bv = bias[col];
#pragma unroll
    for (int i = 0; i < 4; ++i) {
#pragma unroll
      for (int r = 0; r < 4; ++r) {
        const int row = m0 + i * 16 + kq * 4 + r;
        C[(size_t)row * N + col] = acc[i][j][r] * inv + bv;
      }
    }
  }
#undef STAGE
}

// ---------------- fallback fp32 GEMM (proven) ----------------
#define BM 128
#define BN 64
#define BKK 8
#define TM 8
#define TN 4

__global__ __launch_bounds__(256) void sgemm_nt(
    const float* __restrict__ A, const float* __restrict__ B,
    const float* __restrict__ bias, float* __restrict__ C,
    int M, int N, int K) {
  __shared__ float As[BKK][BM];
  __shared__ float Bs[BKK][BN];

  const int tid = threadIdx.x;
  const int tn = tid & 15;
  const int tm = tid >> 4;
  const int bx = blockIdx.x;
  const int by = blockIdx.y;

  const float* Ab = A + (size_t)by * BM * K;
  const float* Bb = B + (size_t)bx * BN * K;

  const int ar = tid >> 1;
  const int ak = (tid & 1) * 4;

  float acc[TM][TN];
#pragma unroll
  for (int i = 0; i < TM; ++i)
#pragma unroll
    for (int j = 0; j < TN; ++j) acc[i][j] = 0.f;

  for (int k0 = 0; k0 < K; k0 += BKK) {
    float4 av = *(const float4*)(Ab + (size_t)ar * K + k0 + ak);
    float4 bv = make_float4(0.f, 0.f, 0.f, 0.f);
    if (tid < 128) bv = *(const float4*)(Bb + (size_t)ar * K + k0 + ak);

    __syncthreads();
    As[ak + 0][ar] = av.x;
    As[ak + 1][ar] = av.y;
    As[ak + 2][ar] = av.z;
    As[ak + 3][ar] = av.w;
    if (tid < 128) {
      Bs[ak + 0][ar] = bv.x;
      Bs[ak + 1][ar] = bv.y;
      Bs[ak + 2][ar] = bv.z;
      Bs[ak + 3][ar] = bv.w;
    }
    __syncthreads();

#pragma unroll
    for (int kk = 0; kk < BKK; ++kk) {
      float a[TM], b[TN];
#pragma unroll
      for (int i = 0; i < TM; ++i) a[i] = As[kk][tm * TM + i];
#pragma unroll
      for (int j = 0; j < TN; ++j) b[j] = Bs[kk][tn * TN + j];
#pragma unroll
      for (int i = 0; i < TM; ++i)
#pragma unroll
        for (int j = 0; j < TN; ++j) acc[i][j] += a[i] * b[j];
    }
  }

  const int row0 = by * BM + tm * TM;
  const int col0 = bx * BN + tn * TN;
  float bj[TN];
#pragma unroll
  for (int j = 0; j < TN; ++j) bj[j] = bias[col0 + j];
#pragma unroll
  for (int i = 0; i < TM; ++i) {
    float4 v = make_float4(acc[i][0] + bj[0], acc[i][1] + bj[1],
                           acc[i][2] + bj[2], acc[i][3] + bj[3]);
    *(float4*)(C + (size_t)(row0 + i) * N + col0) = v;
  }
}

// ---------------- Hadamard + banded quant-dequant + inverse ----------------
__device__ inline void fwht2(float& e0, float& e1, int lane) {
  float a = e0 + e1;
  float b = e0 - e1;
  e0 = a;
  e1 = b;
#pragma unroll
  for (int s = 1; s <= 32; s <<= 1) {
    float p0 = __shfl_xor(e0, s);
    float p1 = __shfl_xor(e1, s);
    bool up = (lane & s) != 0;
    e0 = up ? (p0 - e0) : (e0 + p0);
    e1 = up ? (p1 - e1) : (e1 + p1);
  }
}

__global__ __launch_bounds__(256) void hadq(const float* __restrict__ Y,
                                            float* __restrict__ O, int nrows) {
  const int lane = threadIdx.x & 63;
  const int wave = (blockIdx.x * (blockDim.x >> 6)) + (threadIdx.x >> 6);
  const int nwaves = gridDim.x * (blockDim.x >> 6);

  const int b0 = g_tbl.band[lane];
  const int b1 = g_tbl.band[lane + 64];
  const float qm0 = g_tbl.qm[lane];
  const float qm1 = g_tbl.qm[lane + 64];

  for (int row = wave; row < nrows; row += nwaves) {
    const float* y = Y + (size_t)row * HEAD;
    float e0 = y[lane];
    float e1 = y[lane + 64];

    fwht2(e0, e1, lane);

    float f0 = fabsf(e0), f1 = fabsf(e1);
    float ab0 = fmaxf(b0 == 0 ? f0 : 0.f, b1 == 0 ? f1 : 0.f);
    float ab1 = fmaxf(b0 == 1 ? f0 : 0.f, b1 == 1 ? f1 : 0.f);
    float ab2 = fmaxf(b0 == 2 ? f0 : 0.f, b1 == 2 ? f1 : 0.f);
    float ab3 = fmaxf(b0 == 3 ? f0 : 0.f, b1 == 3 ? f1 : 0.f);
#pragma unroll
    for (int s = 32; s >= 1; s >>= 1) {
      ab0 = fmaxf(ab0, __shfl_xor(ab0, s));
      ab1 = fmaxf(ab1, __shfl_xor(ab1, s));
      ab2 = fmaxf(ab2, __shfl_xor(ab2, s));
      ab3 = fmaxf(ab3, __shfl_xor(ab3, s));
    }
    float am0 = b0 == 0 ? ab0 : (b0 == 1 ? ab1 : (b0 == 2 ? ab2 : ab3));
    float am1 = b1 == 0 ? ab0 : (b1 == 1 ? ab1 : (b1 == 2 ? ab2 : ab3));

    float s0 = am0 > 0.f ? am0 / qm0 : 1.0f;
    float s1 = am1 > 0.f ? am1 / qm1 : 1.0f;

    float q0 = fminf(fmaxf(rintf(e0 / s0), -qm0), qm0);
    float q1 = fminf(fmaxf(rintf(e1 / s1), -qm1), qm1);
    e0 = q0 * s0;
    e1 = q1 * s1;

    fwht2(e0, e1, lane);
    float r0 = e0 * 0.0078125f;
    float r1 = e1 * 0.0078125f;
    if (r0 != r0) r0 = 0.f;
    if (r1 != r1) r1 = 0.f;
    r0 = fminf(fmaxf(r0, -65504.f), 65504.f);
    r1 = fminf(fmaxf(r1, -65504.f), 65504.f);

    float* o = O + (size_t)row * HEAD;
    o[lane] = r0;
    o[lane + 64] = r1;
  }
}

// ---------------- launch ----------------
extern "C" void kernel_launch(void* const* d_in, const int* in_sizes, int n_in,
                              void* d_out, int out_size, void* d_ws, size_t ws_size,
                              hipStream_t stream) {
  const float* x = (const float*)d_in[0];
  const float* W = (const float*)d_in[1];
  const float* b = (const float*)d_in[2];
  float* out = (float*)d_out;

  const int N = in_sizes[2];      // 5120
  const int K = N;                // 5120
  const int M = in_sizes[0] / K;  // 1024

  const size_t MK = (size_t)M * K;
  const size_t NK = (size_t)N * K;
  const size_t need = (MK + NK) * 2 * sizeof(f16);  // hi+lo for x and W

  if (ws_size >= need) {
    f16* xh = (f16*)d_ws;
    f16* xl = xh + MK;
    f16* wh = xl + MK;
    f16* wl = wh + NK;

    const long n8x = (long)(MK / 8);
    const long n8tot = (long)((MK + NK) / 8);
    split_all<<<4096, 256, 0, stream>>>(x, W, xh, xl, wh, wl, n8x, n8tot);

    dim3 grid(M / 64, N / 64);  // 16 x 80 = 1280 blocks, 5/CU
    gemm_f16split<<<grid, 64, 0, stream>>>(xh, xl, wh, wl, b, out, M, N, K);
  } else {
    dim3 grid(N / BN, M / BM);
    sgemm_nt<<<grid, 256, 0, stream>>>(x, W, b, out, M, N, K);
  }

  const int nrows = out_size / HEAD;
  hadq<<<512, 256, 0, stream>>>(out, out, nrows);
}

// Round 6
// 571.121 us; speedup vs baseline: 1.2990x; 1.2990x over previous
//
#include <hip/hip_runtime.h>
#include <math.h>

#define HEAD 128
typedef _Float16 f16;
typedef _Float16 f16x8 __attribute__((ext_vector_type(8)));
typedef float f32x4 __attribute__((ext_vector_type(4)));

// ---------------- compile-time Möbius band table ----------------
constexpr int mu_of(int n) {
  int m = n, cnt = 0;
  for (int p = 2; p * p <= m; ++p) {
    if (m % p == 0) {
      m /= p; ++cnt;
      if (m % p == 0) return 0;
    }
  }
  if (m > 1) ++cnt;
  return (cnt & 1) ? -1 : 1;
}
constexpr int key_of(int idx) {
  int mu = mu_of(idx + 1);
  return mu == 1 ? 0 : (mu == 0 ? 1 : 2);
}
struct Tbl {
  int band[HEAD];
  float qm[HEAD];
};
constexpr Tbl make_tbl() {
  Tbl t{};
  constexpr float qv[4] = {15.f, 7.f, 7.f, 3.f};
  for (int p = 0; p < HEAD; ++p) {
    int kp = key_of(p);
    int rank = 0;
    for (int j = 0; j < HEAD; ++j) {
      int kj = key_of(j);
      if (kj < kp || (kj == kp && j < p)) ++rank;
    }
    t.band[p] = rank >> 5;
    t.qm[p] = qv[rank >> 5];
  }
  return t;
}
__constant__ Tbl g_tbl = make_tbl();

// ------- fused f32 -> (hi,lo) f16 split for x and W, pre-scaled by 64 ------
__global__ __launch_bounds__(256) void split_all(
    const float* __restrict__ x, const float* __restrict__ W,
    f16* __restrict__ xh, f16* __restrict__ xl,
    f16* __restrict__ wh, f16* __restrict__ wl,
    long n8x, long n8tot) {
  long i = blockIdx.x * (long)blockDim.x + threadIdx.x;
  long stride = (long)gridDim.x * blockDim.x;
  for (; i < n8tot; i += stride) {
    const float* s;
    f16 *h, *l;
    long j;
    if (i < n8x) {
      s = x; h = xh; l = xl; j = i;
    } else {
      s = W; h = wh; l = wl; j = i - n8x;
    }
    const float4* p = (const float4*)s + 2 * j;
    float4 a = p[0], c = p[1];
    float v[8] = {a.x, a.y, a.z, a.w, c.x, c.y, c.z, c.w};
    f16x8 hv, lv;
#pragma unroll
    for (int t = 0; t < 8; ++t) {
      float sv = v[t] * 64.f;
      f16 ht = (f16)sv;
      hv[t] = ht;
      lv[t] = (f16)(sv - (float)ht);
    }
    ((f16x8*)h)[j] = hv;
    ((f16x8*)l)[j] = lv;
  }
}

// ---------------- async global->LDS, 16B ----------------
__device__ __forceinline__ void dma16(const f16* g, const f16* l) {
  __builtin_amdgcn_global_load_lds(
      (const __attribute__((address_space(1))) unsigned int*)g,
      (__attribute__((address_space(3))) unsigned int*)l, 16, 0, 0);
}

// ---------------- MFMA GEMM: C[M,N] = (Ah+Al)(Bh+Bl)^T /4096 + bias --------
// 4 waves/block (m97 shape); block tile 128x64, wave tile 64x32; BK=32.
// Chunk-major staging: panel = 16 rows x 32 cols at panel*512 + lane*8;
// frag addr = panel*512 + frow*8 + kq*128 -> 0 bank conflicts (verified R4).
__global__ __launch_bounds__(256) void gemm_f16split(
    const f16* __restrict__ Ah, const f16* __restrict__ Al,
    const f16* __restrict__ Bh, const f16* __restrict__ Bl,
    const float* __restrict__ bias, float* __restrict__ C,
    int M, int N, int K) {
  __shared__ f16 sAh[4096], sAl[4096];  // 8 panels each (128 rows)
  __shared__ f16 sBh[2048], sBl[2048];  // 4 panels each (64 rows)

  const int tid = threadIdx.x;
  const int lane = tid & 63;
  const int wid = tid >> 6;  // 0..3
  const int m0 = blockIdx.x * 128;
  const int n0 = blockIdx.y * 64;

  // ---- staging assignment: each wave stages 4 A-panels + 2 B-panels ----
  // wid&2 selects hi/lo matrix; wid&1 selects panel half.
  const int srow = lane & 15;
  const int scol = (lane >> 4) * 8;
  const int apo = (wid & 1) * 4;  // A panel offset: 0 or 4
  const int bpo = (wid & 1) * 2;  // B panel offset: 0 or 2
  const f16* gA = ((wid & 2) ? Al : Ah) + (size_t)(m0 + apo * 16 + srow) * K + scol;
  const f16* gB = ((wid & 2) ? Bl : Bh) + (size_t)(n0 + bpo * 16 + srow) * K + scol;
  f16* sA_my = ((wid & 2) ? sAl : sAh) + apo * 512;
  f16* sB_my = ((wid & 2) ? sBl : sBh) + bpo * 512;
  const size_t rstep = (size_t)16 * K;  // 16 rows

#define STAGE(kofs)                                    \
  do {                                                 \
    _Pragma("unroll") for (int q = 0; q < 4; ++q)      \
        dma16(gA + (kofs) + q * rstep, sA_my + q * 512); \
    _Pragma("unroll") for (int q = 0; q < 2; ++q)      \
        dma16(gB + (kofs) + q * rstep, sB_my + q * 512); \
  } while (0)

  f32x4 acc[4][2];
#pragma unroll
  for (int i = 0; i < 4; ++i)
#pragma unroll
    for (int j = 0; j < 2; ++j) acc[i][j] = (f32x4){0.f, 0.f, 0.f, 0.f};

  STAGE(0);

  // ---- compute assignment: wave (wr,wc) owns rows wr*64.., cols wc*32.. ----
  const int wr = wid & 1;
  const int wc = wid >> 1;
  const int frow = lane & 15;
  const int kq = lane >> 4;  // 0..3
  const int fbase = frow * 8 + kq * 128;

  const int nIter = K / 32;
  for (int it = 0; it < nIter; ++it) {
    __syncthreads();  // tile resident (drains vmcnt)
    f16x8 ah[4], al[4], bh[2], bl[2];
#pragma unroll
    for (int s = 0; s < 4; ++s) {
      ah[s] = *(const f16x8*)&sAh[(wr * 4 + s) * 512 + fbase];
      al[s] = *(const f16x8*)&sAl[(wr * 4 + s) * 512 + fbase];
    }
#pragma unroll
    for (int j = 0; j < 2; ++j) {
      bh[j] = *(const f16x8*)&sBh[(wc * 2 + j) * 512 + fbase];
      bl[j] = *(const f16x8*)&sBl[(wc * 2 + j) * 512 + fbase];
    }
    __syncthreads();  // frags in regs; LDS reusable
    if (it + 1 < nIter) STAGE((size_t)(it + 1) * 32);

#pragma unroll
    for (int i = 0; i < 4; ++i)
#pragma unroll
      for (int j = 0; j < 2; ++j) {
        acc[i][j] = __builtin_amdgcn_mfma_f32_16x16x32_f16(ah[i], bh[j], acc[i][j], 0, 0, 0);
        acc[i][j] = __builtin_amdgcn_mfma_f32_16x16x32_f16(al[i], bh[j], acc[i][j], 0, 0, 0);
        acc[i][j] = __builtin_amdgcn_mfma_f32_16x16x32_f16(ah[i], bl[j], acc[i][j], 0, 0, 0);
      }
  }

  // epilogue: C/D layout col=lane&15, row=(lane>>4)*4+r
  const float inv = 1.f / 4096.f;
#pragma unroll
  for (int j = 0; j < 2; ++j) {
    const int col = n0 + wc * 32 + j * 16 + frow;
    const float bv = bias[col];
#pragma unroll
    for (int i = 0; i < 4; ++i) {
#pragma unroll
      for (int r = 0; r < 4; ++r) {
        const int row = m0 + wr * 64 + i * 16 + kq * 4 + r;
        C[(size_t)row * N + col] = acc[i][j][r] * inv + bv;
      }
    }
  }
#undef STAGE
}

// ---------------- fallback fp32 GEMM (proven) ----------------
#define BM 128
#define BN 64
#define BKK 8
#define TM 8
#define TN 4

__global__ __launch_bounds__(256) void sgemm_nt(
    const float* __restrict__ A, const float* __restrict__ B,
    const float* __restrict__ bias, float* __restrict__ C,
    int M, int N, int K) {
  __shared__ float As[BKK][BM];
  __shared__ float Bs[BKK][BN];

  const int tid = threadIdx.x;
  const int tn = tid & 15;
  const int tm = tid >> 4;
  const int bx = blockIdx.x;
  const int by = blockIdx.y;

  const float* Ab = A + (size_t)by * BM * K;
  const float* Bb = B + (size_t)bx * BN * K;

  const int ar = tid >> 1;
  const int ak = (tid & 1) * 4;

  float acc[TM][TN];
#pragma unroll
  for (int i = 0; i < TM; ++i)
#pragma unroll
    for (int j = 0; j < TN; ++j) acc[i][j] = 0.f;

  for (int k0 = 0; k0 < K; k0 += BKK) {
    float4 av = *(const float4*)(Ab + (size_t)ar * K + k0 + ak);
    float4 bv = make_float4(0.f, 0.f, 0.f, 0.f);
    if (tid < 128) bv = *(const float4*)(Bb + (size_t)ar * K + k0 + ak);

    __syncthreads();
    As[ak + 0][ar] = av.x;
    As[ak + 1][ar] = av.y;
    As[ak + 2][ar] = av.z;
    As[ak + 3][ar] = av.w;
    if (tid < 128) {
      Bs[ak + 0][ar] = bv.x;
      Bs[ak + 1][ar] = bv.y;
      Bs[ak + 2][ar] = bv.z;
      Bs[ak + 3][ar] = bv.w;
    }
    __syncthreads();

#pragma unroll
    for (int kk = 0; kk < BKK; ++kk) {
      float a[TM], b[TN];
#pragma unroll
      for (int i = 0; i < TM; ++i) a[i] = As[kk][tm * TM + i];
#pragma unroll
      for (int j = 0; j < TN; ++j) b[j] = Bs[kk][tn * TN + j];
#pragma unroll
      for (int i = 0; i < TM; ++i)
#pragma unroll
        for (int j = 0; j < TN; ++j) acc[i][j] += a[i] * b[j];
    }
  }

  const int row0 = by * BM + tm * TM;
  const int col0 = bx * BN + tn * TN;
  float bj[TN];
#pragma unroll
  for (int j = 0; j < TN; ++j) bj[j] = bias[col0 + j];
#pragma unroll
  for (int i = 0; i < TM; ++i) {
    float4 v = make_float4(acc[i][0] + bj[0], acc[i][1] + bj[1],
                           acc[i][2] + bj[2], acc[i][3] + bj[3]);
    *(float4*)(C + (size_t)(row0 + i) * N + col0) = v;
  }
}

// ---------------- Hadamard + banded quant-dequant + inverse ----------------
__device__ inline void fwht2(float& e0, float& e1, int lane) {
  float a = e0 + e1;
  float b = e0 - e1;
  e0 = a;
  e1 = b;
#pragma unroll
  for (int s = 1; s <= 32; s <<= 1) {
    float p0 = __shfl_xor(e0, s);
    float p1 = __shfl_xor(e1, s);
    bool up = (lane & s) != 0;
    e0 = up ? (p0 - e0) : (e0 + p0);
    e1 = up ? (p1 - e1) : (e1 + p1);
  }
}

__global__ __launch_bounds__(256) void hadq(const float* __restrict__ Y,
                                            float* __restrict__ O, int nrows) {
  const int lane = threadIdx.x & 63;
  const int wave = (blockIdx.x * (blockDim.x >> 6)) + (threadIdx.x >> 6);
  const int nwaves = gridDim.x * (blockDim.x >> 6);

  const int b0 = g_tbl.band[lane];
  const int b1 = g_tbl.band[lane + 64];
  const float qm0 = g_tbl.qm[lane];
  const float qm1 = g_tbl.qm[lane + 64];

  for (int row = wave; row < nrows; row += nwaves) {
    const float* y = Y + (size_t)row * HEAD;
    float e0 = y[lane];
    float e1 = y[lane + 64];

    fwht2(e0, e1, lane);

    float f0 = fabsf(e0), f1 = fabsf(e1);
    float ab0 = fmaxf(b0 == 0 ? f0 : 0.f, b1 == 0 ? f1 : 0.f);
    float ab1 = fmaxf(b0 == 1 ? f0 : 0.f, b1 == 1 ? f1 : 0.f);
    float ab2 = fmaxf(b0 == 2 ? f0 : 0.f, b1 == 2 ? f1 : 0.f);
    float ab3 = fmaxf(b0 == 3 ? f0 : 0.f, b1 == 3 ? f1 : 0.f);
#pragma unroll
    for (int s = 32; s >= 1; s >>= 1) {
      ab0 = fmaxf(ab0, __shfl_xor(ab0, s));
      ab1 = fmaxf(ab1, __shfl_xor(ab1, s));
      ab2 = fmaxf(ab2, __shfl_xor(ab2, s));
      ab3 = fmaxf(ab3, __shfl_xor(ab3, s));
    }
    float am0 = b0 == 0 ? ab0 : (b0 == 1 ? ab1 : (b0 == 2 ? ab2 : ab3));
    float am1 = b1 == 0 ? ab0 : (b1 == 1 ? ab1 : (b1 == 2 ? ab2 : ab3));

    float s0 = am0 > 0.f ? am0 / qm0 : 1.0f;
    float s1 = am1 > 0.f ? am1 / qm1 : 1.0f;

    float q0 = fminf(fmaxf(rintf(e0 / s0), -qm0), qm0);
    float q1 = fminf(fmaxf(rintf(e1 / s1), -qm1), qm1);
    e0 = q0 * s0;
    e1 = q1 * s1;

    fwht2(e0, e1, lane);
    float r0 = e0 * 0.0078125f;
    float r1 = e1 * 0.0078125f;
    if (r0 != r0) r0 = 0.f;
    if (r1 != r1) r1 = 0.f;
    r0 = fminf(fmaxf(r0, -65504.f), 65504.f);
    r1 = fminf(fmaxf(r1, -65504.f), 65504.f);

    float* o = O + (size_t)row * HEAD;
    o[lane] = r0;
    o[lane + 64] = r1;
  }
}

// ---------------- launch ----------------
extern "C" void kernel_launch(void* const* d_in, const int* in_sizes, int n_in,
                              void* d_out, int out_size, void* d_ws, size_t ws_size,
                              hipStream_t stream) {
  const float* x = (const float*)d_in[0];
  const float* W = (const float*)d_in[1];
  const float* b = (const float*)d_in[2];
  float* out = (float*)d_out;

  const int N = in_sizes[2];      // 5120
  const int K = N;                // 5120
  const int M = in_sizes[0] / K;  // 1024

  const size_t MK = (size_t)M * K;
  const size_t NK = (size_t)N * K;
  const size_t need = (MK + NK) * 2 * sizeof(f16);  // hi+lo for x and W

  if (ws_size >= need) {
    f16* xh = (f16*)d_ws;
    f16* xl = xh + MK;
    f16* wh = xl + MK;
    f16* wl = wh + NK;

    const long n8x = (long)(MK / 8);
    const long n8tot = (long)((MK + NK) / 8);
    split_all<<<4096, 256, 0, stream>>>(x, W, xh, xl, wh, wl, n8x, n8tot);

    dim3 grid(M / 128, N / 64);  // 8 x 80 = 640 blocks, 2.5/CU, 10 waves/CU
    gemm_f16split<<<grid, 256, 0, stream>>>(xh, xl, wh, wl, b, out, M, N, K);
  } else {
    dim3 grid(N / BN, M / BM);
    sgemm_nt<<<grid, 256, 0, stream>>>(x, W, b, out, M, N, K);
  }

  const int nrows = out_size / HEAD;
  hadq<<<512, 256, 0, stream>>>(out, out, nrows);
}